// Round 4
// baseline (390.984 us; speedup 1.0000x reference)
//
#include <hip/hip_runtime.h>
#include <hip/hip_bf16.h>
#include <hip/hip_cooperative_groups.h>

namespace cg = cooperative_groups;

#define NR 8192
#define KF 512
#define OF 256

// ws float offsets
#define WS_SAP 0          // 256 per-block Sa partials
#define WS_SBP 256        // 256 per-block Sb partials
#define WS_U   512        // 256
#define WS_V   768        // 256
#define WS_PU  1024       // 256 blocks x 256
#define WS_PV  66560      // 256 blocks x 256
#define WS_FLOATS 132096
#define WS_BT_BYTES (WS_FLOATS * 4)   // 528384, 16B-aligned

#define HS 257            // H LDS row stride (conflict-free MFMA writes + row reads)

typedef float f32x4 __attribute__((ext_vector_type(4)));
typedef __bf16 bf16x8 __attribute__((ext_vector_type(8)));

__global__ __launch_bounds__(512, 1) void k_fused(
        const float* __restrict__ input,
        const float* __restrict__ w_s,
        const float* __restrict__ w_r,
        const float* __restrict__ weight,
        float* __restrict__ ws,
        __hip_bfloat16* __restrict__ BtH,
        float* __restrict__ out) {
    __shared__ float H[32 * HS];          // 32.9 KB, persistent B -> D
    __shared__ float scratch[64 * 65];    // 16.6 KB: transpose tile (A) / Sa-Sb reduce (B)
    __shared__ float pl[32], ql[32], al[32], bl[32], gl[32];
    __shared__ float sAB[2];

    const int tid  = threadIdx.x;
    const int blk  = blockIdx.x;
    const int base = blk * 32;
    __bf16* Bt = (__bf16*)BtH;

    // ================= Phase A =================
    // per-block partial sums of |w_s|, |w_r| over rows [base, base+32)
    if (tid < 64) {
        float la = 0.f, lb = 0.f;
        if (tid < 32) { la = fabsf(w_s[base + tid]); lb = fabsf(w_r[base + tid]); }
#pragma unroll
        for (int o = 16; o > 0; o >>= 1) {
            la += __shfl_down(la, o);
            lb += __shfl_down(lb, o);
        }
        if (tid == 0) { ws[WS_SAP + blk] = la; ws[WS_SBP + blk] = lb; }
    }
    // weight [512][256] f32 -> Bt [256][512] bf16 (blocks 0..31, one 64x64 tile each)
    if (blk < 32) {
        float (*tile)[65] = (float (*)[65])scratch;
        const int k0 = (blk & 7) * 64;
        const int c0 = (blk >> 3) * 64;
#pragma unroll
        for (int it = 0; it < 8; ++it) {
            const int idx = it * 512 + tid;
            tile[idx >> 6][idx & 63] = weight[(k0 + (idx >> 6)) * OF + c0 + (idx & 63)];
        }
        __syncthreads();
#pragma unroll
        for (int it = 0; it < 8; ++it) {
            const int idx = it * 512 + tid;
            Bt[(c0 + (idx >> 6)) * KF + k0 + (idx & 63)] = (__bf16)tile[idx & 63][idx >> 6];
        }
    }
    __threadfence();
    cg::this_grid().sync();
    __threadfence();

    // ================= Phase B =================
    // Sa/Sb: every block reduces the 256 partials (L2-hot, cheap)
    {
        float* sA = scratch;
        float* sB = scratch + 256;
        if (tid < 256) { sA[tid] = ws[WS_SAP + tid]; sB[tid] = ws[WS_SBP + tid]; }
        __syncthreads();
        for (int s = 128; s > 0; s >>= 1) {
            if (tid < s) { sA[tid] += sA[tid + s]; sB[tid] += sB[tid + s]; }
            __syncthreads();
        }
        if (tid == 0) { sAB[0] = sA[0]; sAB[1] = sB[0]; }
        __syncthreads();
    }
    // per-row scalars for this block's 32 rows (LDS only)
    if (tid < 32) {
        const int row = base + tid;
        const float a = fabsf(w_s[row]);
        const float b = fabsf(w_r[row]);
        const float Sa = sAB[0], Sb = sAB[1];
        float s = 0.5f * (a * (Sb - b) + b * (Sa - a));
        if (s == 0.f) s = 1.f;
        const float d = 1.0f / sqrtf(s);
        al[tid] = 0.5f * d * a;
        bl[tid] = 0.5f * d * b;
        gl[tid] = d * d * a * b;
        pl[tid] = d * b;
        ql[tid] = d * a;
    }
    // H-tile (32 rows x 256 cols) via MFMA; wave w: row-tile (w>>2), col-group (w&3)
    {
        const int w    = tid >> 6;
        const int l    = tid & 63;
        const int t    = w >> 2;
        const int cgp  = w & 3;
        const int lrow = l & 15;
        const int lkh  = (l >> 4) * 8;
        const float*  ap0 = input + (base + t * 16 + lrow) * KF + lkh;
        const __bf16* bp0 = Bt + (cgp * 64 + lrow) * KF + lkh;
        f32x4 acc0 = {0.f,0.f,0.f,0.f}, acc1 = {0.f,0.f,0.f,0.f};
        f32x4 acc2 = {0.f,0.f,0.f,0.f}, acc3 = {0.f,0.f,0.f,0.f};
#pragma unroll
        for (int ks = 0; ks < 16; ++ks) {
            const int k0 = ks * 32;
            const f32x4 alo = *(const f32x4*)(ap0 + k0);
            const f32x4 ahi = *(const f32x4*)(ap0 + k0 + 4);
            bf16x8 af;
            af[0]=(__bf16)alo[0]; af[1]=(__bf16)alo[1]; af[2]=(__bf16)alo[2]; af[3]=(__bf16)alo[3];
            af[4]=(__bf16)ahi[0]; af[5]=(__bf16)ahi[1]; af[6]=(__bf16)ahi[2]; af[7]=(__bf16)ahi[3];
            const bf16x8 b0 = *(const bf16x8*)(bp0 + 0 * 16 * KF + k0);
            const bf16x8 b1 = *(const bf16x8*)(bp0 + 1 * 16 * KF + k0);
            const bf16x8 b2 = *(const bf16x8*)(bp0 + 2 * 16 * KF + k0);
            const bf16x8 b3 = *(const bf16x8*)(bp0 + 3 * 16 * KF + k0);
            acc0 = __builtin_amdgcn_mfma_f32_16x16x32_bf16(af, b0, acc0, 0, 0, 0);
            acc1 = __builtin_amdgcn_mfma_f32_16x16x32_bf16(af, b1, acc1, 0, 0, 0);
            acc2 = __builtin_amdgcn_mfma_f32_16x16x32_bf16(af, b2, acc2, 0, 0, 0);
            acc3 = __builtin_amdgcn_mfma_f32_16x16x32_bf16(af, b3, acc3, 0, 0, 0);
        }
        const int hr = t * 16 + (l >> 4) * 4;
        const int hc = cgp * 64 + lrow;
#pragma unroll
        for (int r = 0; r < 4; ++r) {
            H[(hr + r) * HS + hc +  0] = acc0[r];
            H[(hr + r) * HS + hc + 16] = acc1[r];
            H[(hr + r) * HS + hc + 32] = acc2[r];
            H[(hr + r) * HS + hc + 48] = acc3[r];
        }
    }
    __syncthreads();
    // per-block partial U/V: pU[k] = sum_r pl[r] * H[r][k]   (row-broadcast reads)
    {
        const int k = tid & 255;
        const float* pv = (tid < 256) ? pl : ql;
        float u = 0.f;
#pragma unroll 8
        for (int r = 0; r < 32; ++r) u += pv[r] * H[r * HS + k];
        if (tid < 256) ws[WS_PU + blk * 256 + k] = u;
        else           ws[WS_PV + blk * 256 + k] = u;
    }
    __threadfence();
    cg::this_grid().sync();
    __threadfence();

    // ================= Phase C =================
    // blocks 0..7 reduce U, 8..15 reduce V (no atomics; disjoint k ownership)
    if (blk < 16) {
        const bool isV = blk >= 8;
        const int  g   = blk & 7;
        const int  k   = g * 32 + (tid >> 4);
        const int  b0  = tid & 15;
        const int  off = isV ? WS_PV : WS_PU;
        float s = 0.f;
#pragma unroll
        for (int j = 0; j < 16; ++j) s += ws[off + (b0 + 16 * j) * 256 + k];
#pragma unroll
        for (int o = 8; o > 0; o >>= 1) s += __shfl_down(s, o);
        if (b0 == 0) ws[(isV ? WS_V : WS_U) + k] = s;
    }
    __threadfence();
    cg::this_grid().sync();
    __threadfence();

    // ================= Phase D =================
    // out[row][k] = al*U[k] + bl*V[k] - gl*H[row][k]
    {
        const int k    = tid & 255;
        const int half = tid >> 8;
        const float Uk = ws[WS_U + k];
        const float Vk = ws[WS_V + k];
        float* op = out + (base + half * 16) * OF + k;
#pragma unroll
        for (int i = 0; i < 16; ++i) {
            const int row = half * 16 + i;
            op[i * OF] = al[row] * Uk + bl[row] * Vk - gl[row] * H[row * HS + k];
        }
    }
}

// ---------------------------------------------------------------------------
extern "C" void kernel_launch(void* const* d_in, const int* in_sizes, int n_in,
                              void* d_out, int out_size, void* d_ws, size_t ws_size,
                              hipStream_t stream) {
    const float* input  = (const float*)d_in[0];
    const float* w_s    = (const float*)d_in[1];
    const float* w_r    = (const float*)d_in[2];
    const float* weight = (const float*)d_in[3];
    float* ws = (float*)d_ws;
    __hip_bfloat16* Bt = (__hip_bfloat16*)((char*)d_ws + WS_BT_BYTES);
    float* out = (float*)d_out;

    void* args[] = {(void*)&input, (void*)&w_s, (void*)&w_r, (void*)&weight,
                    (void*)&ws, (void*)&Bt, (void*)&out};
    hipLaunchCooperativeKernel((void*)k_fused, dim3(256), dim3(512), args, 0, stream);
}

// Round 5
// 92.640 us; speedup vs baseline: 4.2205x; 4.2205x over previous
//
#include <hip/hip_runtime.h>
#include <hip/hip_bf16.h>

#define NR 8192
#define KF 512
#define OF 256

// ws float offsets
#define WS_AL   0        // alpha [8192]
#define WS_BE   8192     // beta  [8192]
#define WS_GA   16384    // gamma [8192]
#define WS_PU   24576    // 256 blocks x 256
#define WS_PV   90112    // 256 blocks x 256
#define WS_U    155648   // 256
#define WS_V    155904   // 256
#define HB_BYTE_OFF 624640   // bf16 H [8192][256], 16B-aligned

typedef float f32x4 __attribute__((ext_vector_type(4)));
typedef __bf16 bf16x8 __attribute__((ext_vector_type(8)));

// ---------------------------------------------------------------------------
// k1: 256 blocks x 512 thr, 32 rows each.
//  - local Sa/Sb (full 8192-sum per block, L2-hot)
//  - alpha/beta/gamma -> ws ; p/q -> LDS
//  - H tile (32x256) via MFMA, W transposed to LDS bf16 in 128-k chunks
//  - partial U/V -> ws ; H -> bf16 -> ws
// ---------------------------------------------------------------------------
__global__ __launch_bounds__(512, 1) void k1(const float* __restrict__ input,
                                             const float* __restrict__ w_s,
                                             const float* __restrict__ w_r,
                                             const float* __restrict__ weight,
                                             float* __restrict__ ws,
                                             __hip_bfloat16* __restrict__ HbH) {
    __shared__ float H[32 * 257];          // 32.9 KB
    __shared__ __bf16 Wt[256][136];        // 69.6 KB, [col][k-chunk], pad->conflict-lite
    __shared__ float pl[32], ql[32];
    __shared__ float red[16];

    const int tid  = threadIdx.x;
    const int blk  = blockIdx.x;
    const int base = blk * 32;
    __bf16* Hb = (__bf16*)HbH;

    // ---- Sa/Sb: full local reduction ----
    float la = 0.f, lb = 0.f;
#pragma unroll
    for (int i = 0; i < 16; ++i) {
        const int idx = tid + (i << 9);
        la += fabsf(w_s[idx]);
        lb += fabsf(w_r[idx]);
    }
#pragma unroll
    for (int o = 32; o > 0; o >>= 1) {
        la += __shfl_down(la, o);
        lb += __shfl_down(lb, o);
    }
    if ((tid & 63) == 0) { red[tid >> 6] = la; red[8 + (tid >> 6)] = lb; }
    __syncthreads();
    float Sa = 0.f, Sb = 0.f;
#pragma unroll
    for (int i = 0; i < 8; ++i) { Sa += red[i]; Sb += red[8 + i]; }

    // ---- per-row scalars ----
    if (tid < 32) {
        const int row = base + tid;
        const float a = fabsf(w_s[row]);
        const float b = fabsf(w_r[row]);
        float s = 0.5f * (a * (Sb - b) + b * (Sa - a));
        if (s == 0.f) s = 1.f;
        const float d = 1.0f / sqrtf(s);
        ws[WS_AL + row] = 0.5f * d * a;
        ws[WS_BE + row] = 0.5f * d * b;
        ws[WS_GA + row] = d * d * a * b;
        pl[tid] = d * b;
        ql[tid] = d * a;
    }
    __syncthreads();

    // ---- MFMA over 4 K-chunks of 128 ----
    const int w       = tid >> 6;
    const int l       = tid & 63;
    const int rowhalf = w >> 2;
    const int cgrp    = w & 3;
    const int lrow    = l & 15;
    const int khalf   = l >> 4;

    f32x4 acc0 = {0.f,0.f,0.f,0.f}, acc1 = {0.f,0.f,0.f,0.f};
    f32x4 acc2 = {0.f,0.f,0.f,0.f}, acc3 = {0.f,0.f,0.f,0.f};

    const int cW  = tid & 255;
    const int kg0 = tid >> 8;

    for (int ch = 0; ch < 4; ++ch) {
        // build Wt[c][k] bf16 via transposed-but-coalesced global reads (L2-hot)
#pragma unroll
        for (int j = 0; j < 8; ++j) {
            const int k0 = (kg0 + 2 * j) * 8;          // local k octet
            const int kg = ch * 128 + k0;
            bf16x8 v;
#pragma unroll
            for (int jj = 0; jj < 8; ++jj)
                v[jj] = (__bf16)weight[(kg + jj) * OF + cW];
            *(bf16x8*)&Wt[cW][k0] = v;
        }
        __syncthreads();
#pragma unroll
        for (int kst = 0; kst < 4; ++kst) {
            const int klocal = kst * 32 + khalf * 8;
            const int kglob  = ch * 128 + klocal;
            const float* ap = input + (base + rowhalf * 16 + lrow) * KF + kglob;
            const f32x4 alo = *(const f32x4*)ap;
            const f32x4 ahi = *(const f32x4*)(ap + 4);
            bf16x8 af;
            af[0]=(__bf16)alo[0]; af[1]=(__bf16)alo[1]; af[2]=(__bf16)alo[2]; af[3]=(__bf16)alo[3];
            af[4]=(__bf16)ahi[0]; af[5]=(__bf16)ahi[1]; af[6]=(__bf16)ahi[2]; af[7]=(__bf16)ahi[3];
            const bf16x8 b0 = *(const bf16x8*)&Wt[cgrp * 64 +  0 + lrow][klocal];
            const bf16x8 b1 = *(const bf16x8*)&Wt[cgrp * 64 + 16 + lrow][klocal];
            const bf16x8 b2 = *(const bf16x8*)&Wt[cgrp * 64 + 32 + lrow][klocal];
            const bf16x8 b3 = *(const bf16x8*)&Wt[cgrp * 64 + 48 + lrow][klocal];
            acc0 = __builtin_amdgcn_mfma_f32_16x16x32_bf16(af, b0, acc0, 0, 0, 0);
            acc1 = __builtin_amdgcn_mfma_f32_16x16x32_bf16(af, b1, acc1, 0, 0, 0);
            acc2 = __builtin_amdgcn_mfma_f32_16x16x32_bf16(af, b2, acc2, 0, 0, 0);
            acc3 = __builtin_amdgcn_mfma_f32_16x16x32_bf16(af, b3, acc3, 0, 0, 0);
        }
        __syncthreads();
    }

    // ---- H accs -> LDS ----
    {
        const int hr = rowhalf * 16 + khalf * 4;
        const int hc = cgrp * 64 + lrow;
#pragma unroll
        for (int r = 0; r < 4; ++r) {
            H[(hr + r) * 257 + hc +  0] = acc0[r];
            H[(hr + r) * 257 + hc + 16] = acc1[r];
            H[(hr + r) * 257 + hc + 32] = acc2[r];
            H[(hr + r) * 257 + hc + 48] = acc3[r];
        }
    }
    __syncthreads();

    // ---- partial U/V ----
    {
        const int k = tid & 255;
        const float* pv = (tid < 256) ? pl : ql;
        float u = 0.f;
#pragma unroll 8
        for (int r = 0; r < 32; ++r) u += pv[r] * H[r * 257 + k];
        if (tid < 256) ws[WS_PU + blk * 256 + k] = u;
        else           ws[WS_PV + blk * 256 + k] = u;
    }

    // ---- H -> bf16 -> global (lanes span rows: conflict-free LDS reads) ----
    {
        const int row = tid & 31;
        const int c0  = (tid >> 5) * 16;
        const float* hp = &H[row * 257 + c0];
        bf16x8 v0, v1;
#pragma unroll
        for (int j = 0; j < 8; ++j) v0[j] = (__bf16)hp[j];
#pragma unroll
        for (int j = 0; j < 8; ++j) v1[j] = (__bf16)hp[8 + j];
        __bf16* dst = Hb + (base + row) * OF + c0;
        *(bf16x8*)dst       = v0;
        *(bf16x8*)(dst + 8) = v1;
    }
}

// ---------------------------------------------------------------------------
// k2: reduce 256 partials -> U/V. blocks 0..7 = U, 8..15 = V. No atomics.
// ---------------------------------------------------------------------------
__global__ __launch_bounds__(256) void k2(float* __restrict__ ws) {
    const int b   = blockIdx.x;
    const bool isV = b >= 8;
    const int kb  = (b & 7) * 32;
    const int t   = threadIdx.x;
    const int k   = kb + (t >> 3);
    const int p0  = t & 7;
    const float* P = ws + (isV ? WS_PV : WS_PU);
    float s = 0.f;
#pragma unroll 8
    for (int j = p0; j < 256; j += 8) s += P[j * 256 + k];
#pragma unroll
    for (int o = 4; o > 0; o >>= 1) s += __shfl_down(s, o, 8);
    if (p0 == 0) ws[(isV ? WS_V : WS_U) + k] = s;
}

// ---------------------------------------------------------------------------
// k3: epilogue out[i,k] = al*U + be*V - ga*H. 256 blocks x 256 thr, 32 rows.
// ---------------------------------------------------------------------------
__global__ __launch_bounds__(256) void k3(const __hip_bfloat16* __restrict__ HbH,
                                          const float* __restrict__ ws,
                                          float* __restrict__ out) {
    __shared__ float aL[32], bL[32], gL[32], UL[256], VL[256];
    const int tid  = threadIdx.x;
    const int base = blockIdx.x * 32;
    UL[tid] = ws[WS_U + tid];
    VL[tid] = ws[WS_V + tid];
    if (tid < 32) {
        aL[tid] = ws[WS_AL + base + tid];
        bL[tid] = ws[WS_BE + base + tid];
        gL[tid] = ws[WS_GA + base + tid];
    }
    __syncthreads();
    const ushort* Hb = (const ushort*)HbH;
    const int kp = (tid & 127) * 2;
    const int rh = tid >> 7;
    const float u0 = UL[kp], u1 = UL[kp + 1];
    const float v0 = VL[kp], v1 = VL[kp + 1];
#pragma unroll
    for (int i = 0; i < 16; ++i) {
        const int r = rh * 16 + i;
        const unsigned u = *(const unsigned*)(Hb + (base + r) * OF + kp);
        const float h0 = __uint_as_float(u << 16);
        const float h1 = __uint_as_float(u & 0xffff0000u);
        float2 o;
        o.x = aL[r] * u0 + bL[r] * v0 - gL[r] * h0;
        o.y = aL[r] * u1 + bL[r] * v1 - gL[r] * h1;
        *(float2*)(out + (base + r) * OF + kp) = o;
    }
}

// ---------------------------------------------------------------------------
extern "C" void kernel_launch(void* const* d_in, const int* in_sizes, int n_in,
                              void* d_out, int out_size, void* d_ws, size_t ws_size,
                              hipStream_t stream) {
    const float* input  = (const float*)d_in[0];
    const float* w_s    = (const float*)d_in[1];
    const float* w_r    = (const float*)d_in[2];
    const float* weight = (const float*)d_in[3];
    float* ws = (float*)d_ws;
    __hip_bfloat16* Hb = (__hip_bfloat16*)((char*)d_ws + HB_BYTE_OFF);
    float* out = (float*)d_out;

    hipLaunchKernelGGL(k1, dim3(256), dim3(512), 0, stream, input, w_s, w_r, weight, ws, Hb);
    hipLaunchKernelGGL(k2, dim3(16),  dim3(256), 0, stream, ws);
    hipLaunchKernelGGL(k3, dim3(256), dim3(256), 0, stream, Hb, ws, out);
}